// Round 3
// baseline (201.863 us; speedup 1.0000x reference)
//
#include <hip/hip_runtime.h>
#include <math.h>

#define N_DENSE  13
#define N_SPARSE 26
#define VOCAB    100000
#define EMB      64
#define NH       12
#define NPAIR    325
#define NPAD     328       // 325 rounded up so float4 score reads stay in-bounds
#define ESTR     68        // padded row stride (floats): 16B-aligned
#define NWAVE    6
#define BLOCK    384
#define TEMP_INV 10.0f

// Weighted sum over pairs [LO,HI) with embeddings resident in registers.
// i, j, p are all compile-time after full unroll -> e_reg stays in VGPRs.
// Scores are read as one broadcast float4 per 4 pairs (LO must be %4==0).
template<int LO, int HI>
__device__ __forceinline__ float wsum_range(const float (&e_reg)[N_SPARSE],
                                            const float* expv_s)
{
    float acc = 0.0f;
    float4 sq = {0.f, 0.f, 0.f, 0.f};
    #pragma unroll
    for (int i = 0; i < N_SPARSE - 1; ++i) {
        #pragma unroll
        for (int j = i + 1; j < N_SPARSE; ++j) {
            const int p = i * (2 * N_SPARSE - i - 1) / 2 + (j - i - 1);
            if (p >= LO && p < HI) {                      // folds at compile time
                if ((p & 3) == 0)
                    sq = *reinterpret_cast<const float4*>(expv_s + p);
                const float s = ((p & 3) == 0) ? sq.x :
                                ((p & 3) == 1) ? sq.y :
                                ((p & 3) == 2) ? sq.z : sq.w;
                acc = fmaf(s, e_reg[i] * e_reg[j], acc);
            }
        }
    }
    return acc;
}

__global__ __launch_bounds__(BLOCK) void afm_kernel(
    const float* __restrict__ dense_x,
    const int*   __restrict__ sparse_idx,
    const float* __restrict__ emb,
    const float* __restrict__ attn_W,
    const float* __restrict__ attn_b,
    const float* __restrict__ proj_W,
    const float* __restrict__ proj_b,
    const float* __restrict__ lin_W,
    const float* __restrict__ lin_b,
    const float* __restrict__ pred_W,
    const float* __restrict__ pred_b,
    float* __restrict__ out)
{
    const int row  = blockIdx.x;
    const int tid  = threadIdx.x;
    const int lane = tid & 63;
    const int wv   = tid >> 6;

    __shared__ __align__(16) float e_s[N_SPARSE][ESTR];
    __shared__ __align__(16) float expv_s[NPAD];
    __shared__ float redmax_s[NWAVE];
    __shared__ float redsum_s[NWAVE];
    __shared__ float att_s[NWAVE][EMB];
    __shared__ float part1_s;
    __shared__ int   sidx_s[N_SPARSE];

    if (tid < N_SPARSE) sidx_s[tid] = sparse_idx[row * N_SPARSE + tid];
    __syncthreads();

    // ---- gather embeddings into LDS (float4, coalesced 256B rows) ----
    for (int q = tid; q < N_SPARSE * 16; q += BLOCK) {
        int f = q >> 4, d4 = q & 15;
        const float4* src = reinterpret_cast<const float4*>(
            emb + ((size_t)f * VOCAB + (size_t)sidx_s[f]) * EMB);
        reinterpret_cast<float4*>(&e_s[f][0])[d4] = src[d4];
    }

    // ---- part_1 (exact f32), wave 0, lane-parallel over 39 terms ----
    if (wv == 0) {
        float t = 0.0f;
        if (lane < N_DENSE)
            t = dense_x[row * N_DENSE + lane] * lin_W[lane];
        else if (lane < N_DENSE + N_SPARSE)
            t = (float)sidx_s[lane - N_DENSE] * lin_W[lane];
        #pragma unroll
        for (int o = 32; o > 0; o >>= 1) t += __shfl_xor(t, o);
        if (lane == 0) part1_s = t + lin_b[0];
    }
    __syncthreads();

    // ---- attention logits: one pair per thread, UNIFORM control flow ----
    const bool valid = (tid < NPAIR);
    int pc = valid ? tid : 0;
    int i = 0, rem = pc;
    while (rem >= (N_SPARSE - 1 - i)) { rem -= (N_SPARSE - 1 - i); ++i; }
    const int j = i + 1 + rem;

    float h[NH];
    #pragma unroll
    for (int k = 0; k < NH; ++k) h[k] = attn_b[k];

    const float4* ei = reinterpret_cast<const float4*>(&e_s[i][0]);
    const float4* ej = reinterpret_cast<const float4*>(&e_s[j][0]);
    const float4* wg = reinterpret_cast<const float4*>(attn_W);  // uniform -> s_load

    #pragma unroll 2
    for (int d4 = 0; d4 < 16; ++d4) {
        float4 a = ei[d4];
        float4 b = ej[d4];
        float c0 = a.x * b.x, c1 = a.y * b.y, c2 = a.z * b.z, c3 = a.w * b.w;
        const int base = d4 * 12;
        float4 w;
#define WROW(cx, o) \
        w = wg[base + (o)*3 + 0]; \
        h[0] = fmaf(cx, w.x, h[0]);  h[1] = fmaf(cx, w.y, h[1]); \
        h[2] = fmaf(cx, w.z, h[2]);  h[3] = fmaf(cx, w.w, h[3]); \
        w = wg[base + (o)*3 + 1]; \
        h[4] = fmaf(cx, w.x, h[4]);  h[5] = fmaf(cx, w.y, h[5]); \
        h[6] = fmaf(cx, w.z, h[6]);  h[7] = fmaf(cx, w.w, h[7]); \
        w = wg[base + (o)*3 + 2]; \
        h[8] = fmaf(cx, w.x, h[8]);  h[9] = fmaf(cx, w.y, h[9]); \
        h[10] = fmaf(cx, w.z, h[10]); h[11] = fmaf(cx, w.w, h[11]);
        WROW(c0, 0) WROW(c1, 1) WROW(c2, 2) WROW(c3, 3)
#undef WROW
    }

    float lg = proj_b[0];
    #pragma unroll
    for (int k = 0; k < NH; ++k)
        lg = fmaf(fmaxf(h[k], 0.0f), proj_W[k], lg);
    lg *= TEMP_INV;
    if (!valid) lg = -INFINITY;

    // ---- block softmax: max ----
    float lmax = lg;
    #pragma unroll
    for (int o = 32; o > 0; o >>= 1) lmax = fmaxf(lmax, __shfl_xor(lmax, o));
    if (lane == 0) redmax_s[wv] = lmax;
    __syncthreads();
    float gmax = redmax_s[0];
    #pragma unroll
    for (int w2 = 1; w2 < NWAVE; ++w2) gmax = fmaxf(gmax, redmax_s[w2]);

    // ---- exp + sum (unnormalized; 1/gsum folded into epilogue) ----
    float ev = valid ? __expf(lg - gmax) : 0.0f;
    if (valid) expv_s[tid] = ev;
    float lsum = ev;
    #pragma unroll
    for (int o = 32; o > 0; o >>= 1) lsum += __shfl_xor(lsum, o);
    if (lane == 0) redsum_s[wv] = lsum;
    __syncthreads();   // also publishes expv_s
    float gsum = redsum_s[0];
    #pragma unroll
    for (int w2 = 1; w2 < NWAVE; ++w2) gsum += redsum_s[w2];

    // ---- weighted sum: lane = dim, embeddings in registers, pairs unrolled ----
    float e_reg[N_SPARSE];
    #pragma unroll
    for (int f = 0; f < N_SPARSE; ++f) e_reg[f] = e_s[f][lane];

    float acc;
    switch (wv) {
        case 0:  acc = wsum_range<0,   56 >(e_reg, expv_s); break;
        case 1:  acc = wsum_range<56,  112>(e_reg, expv_s); break;
        case 2:  acc = wsum_range<112, 168>(e_reg, expv_s); break;
        case 3:  acc = wsum_range<168, 224>(e_reg, expv_s); break;
        case 4:  acc = wsum_range<224, 280>(e_reg, expv_s); break;
        default: acc = wsum_range<280, 325>(e_reg, expv_s); break;
    }
    att_s[wv][lane] = acc;
    __syncthreads();

    // ---- combine, project, sigmoid ----
    if (wv == 0) {
        float a = 0.0f;
        #pragma unroll
        for (int w2 = 0; w2 < NWAVE; ++w2) a += att_s[w2][lane];
        float v = a * pred_W[lane];
        #pragma unroll
        for (int o = 32; o > 0; o >>= 1) v += __shfl_xor(v, o);
        if (lane == 0) {
            float z = part1_s + v / gsum + pred_b[0];
            out[row] = 1.0f / (1.0f + __expf(-z));
        }
    }
}

extern "C" void kernel_launch(void* const* d_in, const int* in_sizes, int n_in,
                              void* d_out, int out_size, void* d_ws, size_t ws_size,
                              hipStream_t stream)
{
    const float* dense_x = (const float*)d_in[0];
    const int*   sparse  = (const int*)  d_in[1];
    const float* emb     = (const float*)d_in[2];
    const float* attn_W  = (const float*)d_in[3];
    const float* attn_b  = (const float*)d_in[4];
    const float* proj_W  = (const float*)d_in[5];
    const float* proj_b  = (const float*)d_in[6];
    const float* lin_W   = (const float*)d_in[7];
    const float* lin_b   = (const float*)d_in[8];
    const float* pred_W  = (const float*)d_in[9];
    const float* pred_b  = (const float*)d_in[10];
    float* out = (float*)d_out;

    int rows = in_sizes[0] / N_DENSE;   // 8192
    afm_kernel<<<rows, BLOCK, 0, stream>>>(dense_x, sparse, emb, attn_W, attn_b,
                                           proj_W, proj_b, lin_W, lin_b,
                                           pred_W, pred_b, out);
}

// Round 4
// 172.027 us; speedup vs baseline: 1.1734x; 1.1734x over previous
//
#include <hip/hip_runtime.h>
#include <hip/hip_bf16.h>
#include <math.h>

#define N_DENSE  13
#define N_SPARSE 26
#define VOCAB    100000
#define EMB      64
#define NH       12
#define NPAIR    325
#define NPADQ    328      // float4-read padding
#define EBSTR    72       // ushort stride per field row: 144B, 16B aligned
#define TEMP_INV 10.0f

// start(i) = i*(51-i)/2 ; p = start(i) + (j-i-1), sequential in (i,j) triu order.

__global__ __launch_bounds__(128) void afm_kernel(
    const float* __restrict__ dense_x,
    const int*   __restrict__ sparse_idx,
    const float* __restrict__ emb,
    const float* __restrict__ attn_W,
    const float* __restrict__ attn_b,
    const float* __restrict__ proj_W,
    const float* __restrict__ proj_b,
    const float* __restrict__ lin_W,
    const float* __restrict__ lin_b,
    const float* __restrict__ pred_W,
    const float* __restrict__ pred_b,
    float* __restrict__ out)
{
    const int tid  = threadIdx.x;
    const int lane = tid & 63;
    const int wv   = tid >> 6;                       // 0 or 1: wave = row
    const int row  = __builtin_amdgcn_readfirstlane(blockIdx.x * 2 + wv);

    __shared__ __align__(16) unsigned short eb_s[2][N_SPARSE][EBSTR];
    __shared__ __align__(16) float          expv_s[2][NPADQ];

    // ---- gather: lane = dim; uniform row addresses -> s_load; store bf16 ----
    const int* sidx = sparse_idx + row * N_SPARSE;   // uniform base
    #pragma unroll
    for (int f = 0; f < N_SPARSE; ++f) {
        int id = sidx[f];                            // uniform -> scalar load
        float v = emb[((size_t)f * VOCAB + (size_t)id) * EMB + lane];
        __hip_bfloat16 hb = __float2bfloat16(v);
        eb_s[wv][f][lane] = *reinterpret_cast<unsigned short*>(&hb);
    }

    // ---- part_1 term per lane (exact f32): lanes 0..12 dense, 13..38 ids ----
    float p1t = 0.0f;
    if (lane < N_DENSE) {
        p1t = dense_x[row * N_DENSE + lane] * lin_W[lane];
    } else if (lane < N_DENSE + N_SPARSE) {
        int idv = sparse_idx[row * N_SPARSE + (lane - N_DENSE)];
        p1t = (float)idv * lin_W[lane];
    }

    __syncthreads();   // eb_s visible to all lanes of own wave

    // ---- logit pass A: one pair per lane per round; store logits in LDS ----
    const float4* wg = reinterpret_cast<const float4*>(attn_W);  // uniform -> s_load
    float lmax = -INFINITY;

    #pragma unroll 1
    for (int r = 0; r < 6; ++r) {
        int  p     = r * 64 + lane;
        bool valid = (p < NPAIR);
        int  pc    = valid ? p : NPAIR - 1;

        // closed-form decode with +-1 correction (est exact at bucket starts)
        float sf = sqrtf((float)(2601 - 8 * pc));
        int i = (int)((51.0f - sf) * 0.5f);
        int st = (i * (51 - i)) >> 1;
        if (pc < st) { --i; st = (i * (51 - i)) >> 1; }
        else { int st2 = ((i + 1) * (50 - i)) >> 1; if (pc >= st2) { ++i; st = st2; } }
        int j = i + 1 + (pc - st);

        const uint4* ebi = reinterpret_cast<const uint4*>(&eb_s[wv][i][0]);
        const uint4* ebj = reinterpret_cast<const uint4*>(&eb_s[wv][j][0]);

        float h[NH];
        #pragma unroll
        for (int k = 0; k < NH; ++k) h[k] = attn_b[k];

        #pragma unroll
        for (int c = 0; c < 8; ++c) {        // 8 dims per chunk (1 b128 per operand)
            uint4 ua = ebi[c];
            uint4 ub = ebj[c];
#define DIMPAIR(UA, UB, DB)                                                     \
            {                                                                   \
                float a0 = __uint_as_float((UA) << 16);                         \
                float a1 = __uint_as_float((UA) & 0xffff0000u);                 \
                float b0 = __uint_as_float((UB) << 16);                         \
                float b1 = __uint_as_float((UB) & 0xffff0000u);                 \
                float c0 = a0 * b0, c1 = a1 * b1;                               \
                float4 w;                                                       \
                w = wg[(DB) * 3 + 0];                                           \
                h[0] = fmaf(c0, w.x, h[0]);  h[1] = fmaf(c0, w.y, h[1]);        \
                h[2] = fmaf(c0, w.z, h[2]);  h[3] = fmaf(c0, w.w, h[3]);        \
                w = wg[(DB) * 3 + 1];                                           \
                h[4] = fmaf(c0, w.x, h[4]);  h[5] = fmaf(c0, w.y, h[5]);        \
                h[6] = fmaf(c0, w.z, h[6]);  h[7] = fmaf(c0, w.w, h[7]);        \
                w = wg[(DB) * 3 + 2];                                           \
                h[8] = fmaf(c0, w.x, h[8]);  h[9] = fmaf(c0, w.y, h[9]);        \
                h[10] = fmaf(c0, w.z, h[10]); h[11] = fmaf(c0, w.w, h[11]);     \
                w = wg[((DB) + 1) * 3 + 0];                                     \
                h[0] = fmaf(c1, w.x, h[0]);  h[1] = fmaf(c1, w.y, h[1]);        \
                h[2] = fmaf(c1, w.z, h[2]);  h[3] = fmaf(c1, w.w, h[3]);        \
                w = wg[((DB) + 1) * 3 + 1];                                     \
                h[4] = fmaf(c1, w.x, h[4]);  h[5] = fmaf(c1, w.y, h[5]);        \
                h[6] = fmaf(c1, w.z, h[6]);  h[7] = fmaf(c1, w.w, h[7]);        \
                w = wg[((DB) + 1) * 3 + 2];                                     \
                h[8] = fmaf(c1, w.x, h[8]);  h[9] = fmaf(c1, w.y, h[9]);        \
                h[10] = fmaf(c1, w.z, h[10]); h[11] = fmaf(c1, w.w, h[11]);     \
            }
            DIMPAIR(ua.x, ub.x, c * 8 + 0)
            DIMPAIR(ua.y, ub.y, c * 8 + 2)
            DIMPAIR(ua.z, ub.z, c * 8 + 4)
            DIMPAIR(ua.w, ub.w, c * 8 + 6)
#undef DIMPAIR
        }

        float lg = proj_b[0];
        #pragma unroll
        for (int k = 0; k < NH; ++k)
            lg = fmaf(fmaxf(h[k], 0.0f), proj_W[k], lg);
        lg *= TEMP_INV;
        if (!valid) lg = -INFINITY;
        lmax = fmaxf(lmax, lg);
        if (valid) expv_s[wv][p] = lg;       // park logit
    }

    // ---- wave-local softmax (shuffles only) ----
    #pragma unroll
    for (int o = 32; o > 0; o >>= 1) lmax = fmaxf(lmax, __shfl_xor(lmax, o));

    float lsum = 0.0f;
    #pragma unroll
    for (int r = 0; r < 6; ++r) {
        int p = r * 64 + lane;
        if (p < NPAIR) {
            float ev = __expf(expv_s[wv][p] - lmax);   // own-lane readback
            expv_s[wv][p] = ev;
            lsum += ev;
        }
    }
    if (lane < NPADQ - NPAIR) expv_s[wv][NPAIR + lane] = 0.0f;
    #pragma unroll
    for (int o = 32; o > 0; o >>= 1) lsum += __shfl_xor(lsum, o);

    __syncthreads();   // expv_s visible across lanes

    // ---- weighted sum: lane = dim; e in registers; static unrolled pairs ----
    float e_reg[N_SPARSE];
    #pragma unroll
    for (int f = 0; f < N_SPARSE; ++f)
        e_reg[f] = __uint_as_float(((unsigned)eb_s[wv][f][lane]) << 16);

    const float4* evq = reinterpret_cast<const float4*>(&expv_s[wv][0]);
    float  acc = 0.0f;
    float4 sq4 = {0.f, 0.f, 0.f, 0.f};
    #pragma unroll
    for (int i = 0; i < N_SPARSE - 1; ++i) {
        #pragma unroll
        for (int j = i + 1; j < N_SPARSE; ++j) {
            const int p = (i * (51 - i)) / 2 + (j - i - 1);   // sequential
            if ((p & 3) == 0) sq4 = evq[p >> 2];
            const float s = ((p & 3) == 0) ? sq4.x :
                            ((p & 3) == 1) ? sq4.y :
                            ((p & 3) == 2) ? sq4.z : sq4.w;
            acc = fmaf(s, e_reg[i] * e_reg[j], acc);
        }
    }

    // ---- epilogue: dual wave reduce (att.pred_W and part_1), sigmoid ----
    float red  = acc * pred_W[lane];
    float redp = p1t;
    #pragma unroll
    for (int o = 32; o > 0; o >>= 1) {
        red  += __shfl_xor(red,  o);
        redp += __shfl_xor(redp, o);
    }
    if (lane == 0) {
        float z = redp + lin_b[0] + red / lsum + pred_b[0];
        out[row] = 1.0f / (1.0f + __expf(-z));
    }
}

extern "C" void kernel_launch(void* const* d_in, const int* in_sizes, int n_in,
                              void* d_out, int out_size, void* d_ws, size_t ws_size,
                              hipStream_t stream)
{
    const float* dense_x = (const float*)d_in[0];
    const int*   sparse  = (const int*)  d_in[1];
    const float* emb     = (const float*)d_in[2];
    const float* attn_W  = (const float*)d_in[3];
    const float* attn_b  = (const float*)d_in[4];
    const float* proj_W  = (const float*)d_in[5];
    const float* proj_b  = (const float*)d_in[6];
    const float* lin_W   = (const float*)d_in[7];
    const float* lin_b   = (const float*)d_in[8];
    const float* pred_W  = (const float*)d_in[9];
    const float* pred_b  = (const float*)d_in[10];
    float* out = (float*)d_out;

    int rows = in_sizes[0] / N_DENSE;   // 8192
    afm_kernel<<<rows / 2, 128, 0, stream>>>(dense_x, sparse, emb, attn_W, attn_b,
                                             proj_W, proj_b, lin_W, lin_b,
                                             pred_W, pred_b, out);
}

// Round 5
// 105.350 us; speedup vs baseline: 1.9161x; 1.6329x over previous
//
#include <hip/hip_runtime.h>
#include <hip/hip_bf16.h>
#include <math.h>

#define N_DENSE  13
#define N_SPARSE 26
#define VOCAB    100000
#define EMB      64
#define NH       12
#define NPAIR    325
#define NPADQ    328      // float4-read padding for scores
#define EBSTR    72       // ushorts per field row = 144B (16B multiple)
#define TEMP_INV 10.0f

// pair p -> (i,j): start(i) = i*(51-i)/2, p = start(i) + (j-i-1)
// dim-chunk c (8 dims) of field f stored at slot (c + 2f) & 7  [bank swizzle]

__global__ __launch_bounds__(128, 5) void afm_kernel(
    const float* __restrict__ dense_x,
    const int*   __restrict__ sparse_idx,
    const float* __restrict__ emb,
    const float* __restrict__ attn_W,
    const float* __restrict__ attn_b,
    const float* __restrict__ proj_W,
    const float* __restrict__ proj_b,
    const float* __restrict__ lin_W,
    const float* __restrict__ lin_b,
    const float* __restrict__ pred_W,
    const float* __restrict__ pred_b,
    float* __restrict__ out)
{
    const int tid  = threadIdx.x;
    const int lane = tid & 63;
    const int wv   = tid >> 6;                       // wave = row slot
    const int row  = __builtin_amdgcn_readfirstlane(blockIdx.x * 2 + wv);

    __shared__ __align__(16) unsigned short eb_s[2][N_SPARSE][EBSTR];
    __shared__ __align__(16) float          expv_s[2][NPADQ];
    __shared__ __align__(16) float          w_s[EMB * NH];   // attn_W staged

    // ---- stage attn_W into LDS (block-cooperative, float4) ----
    {
        const float4* wg = reinterpret_cast<const float4*>(attn_W);
        float4* wl = reinterpret_cast<float4*>(w_s);
        for (int q = tid; q < (EMB * NH) / 4; q += 128) wl[q] = wg[q];
    }

    // ---- gather embeddings (wave = own row): float4 load, bf16 swizzled store ----
    {
        const int* sidx = sparse_idx + row * N_SPARSE;   // uniform base
        for (int q = lane; q < N_SPARSE * 16; q += 64) {
            int f  = q >> 4;
            int d4 = q & 15;                              // covers dims 4*d4..+3
            int id = sidx[f];
            float4 v = *reinterpret_cast<const float4*>(
                emb + ((size_t)f * VOCAB + (size_t)id) * EMB + d4 * 4);
            __hip_bfloat16 b0 = __float2bfloat16(v.x);
            __hip_bfloat16 b1 = __float2bfloat16(v.y);
            __hip_bfloat16 b2 = __float2bfloat16(v.z);
            __hip_bfloat16 b3 = __float2bfloat16(v.w);
            ushort4 hb;
            hb.x = *reinterpret_cast<unsigned short*>(&b0);
            hb.y = *reinterpret_cast<unsigned short*>(&b1);
            hb.z = *reinterpret_cast<unsigned short*>(&b2);
            hb.w = *reinterpret_cast<unsigned short*>(&b3);
            int c = d4 >> 1;
            int s = (c + 2 * f) & 7;
            unsigned short* dst = &eb_s[wv][0][0] + f * EBSTR + s * 8 + (d4 & 1) * 4;
            *reinterpret_cast<ushort4*>(dst) = hb;       // 8B aligned store
        }
    }

    // ---- part_1 term per lane (exact f32) ----
    float p1t = 0.0f;
    if (lane < N_DENSE) {
        p1t = dense_x[row * N_DENSE + lane] * lin_W[lane];
    } else if (lane < N_DENSE + N_SPARSE) {
        int idv = sparse_idx[row * N_SPARSE + (lane - N_DENSE)];
        p1t = (float)idv * lin_W[lane];
    }

    __syncthreads();   // publishes w_s (cross-wave) and eb_s

    // ---- logit pass: one pair per lane per round ----
    float lmax = -INFINITY;

    #pragma unroll 1
    for (int r = 0; r < 6; ++r) {
        int  p     = r * 64 + lane;
        bool valid = (p < NPAIR);
        int  pc    = valid ? p : NPAIR - 1;

        float sf = sqrtf((float)(2601 - 8 * pc));
        int i = (int)((51.0f - sf) * 0.5f);
        int st = (i * (51 - i)) >> 1;
        if (pc < st) { --i; st = (i * (51 - i)) >> 1; }
        else { int st2 = ((i + 1) * (50 - i)) >> 1; if (pc >= st2) { ++i; st = st2; } }
        int j = i + 1 + (pc - st);

        const unsigned short* bi = &eb_s[wv][0][0] + i * EBSTR;
        const unsigned short* bj = &eb_s[wv][0][0] + j * EBSTR;
        const int swi = 2 * i, swj = 2 * j;

        float h[NH];
        #pragma unroll
        for (int k = 0; k < NH; ++k) h[k] = attn_b[k];

        // opaque offset: blocks LICM from hoisting W reads into VGPRs
        unsigned wbyte = 0;
        asm volatile("" : "+v"(wbyte));
        const char* wbase = reinterpret_cast<const char*>(w_s) + wbyte;

        #pragma unroll
        for (int c = 0; c < 8; ++c) {        // 8 dims per chunk, swizzled slot
            uint4 ua = *reinterpret_cast<const uint4*>(bi + (((c + swi) & 7) << 3));
            uint4 ub = *reinterpret_cast<const uint4*>(bj + (((c + swj) & 7) << 3));
#define WQ(idx) (*reinterpret_cast<const float4*>(wbase + (idx) * 16))
#define DIMPAIR(UA, UB, DB)                                                     \
            {                                                                   \
                float a0 = __uint_as_float((UA) << 16);                         \
                float a1 = __uint_as_float((UA) & 0xffff0000u);                 \
                float b0 = __uint_as_float((UB) << 16);                         \
                float b1 = __uint_as_float((UB) & 0xffff0000u);                 \
                float c0 = a0 * b0, c1 = a1 * b1;                               \
                float4 w;                                                       \
                w = WQ((DB) * 3 + 0);                                           \
                h[0] = fmaf(c0, w.x, h[0]);  h[1] = fmaf(c0, w.y, h[1]);        \
                h[2] = fmaf(c0, w.z, h[2]);  h[3] = fmaf(c0, w.w, h[3]);        \
                w = WQ((DB) * 3 + 1);                                           \
                h[4] = fmaf(c0, w.x, h[4]);  h[5] = fmaf(c0, w.y, h[5]);        \
                h[6] = fmaf(c0, w.z, h[6]);  h[7] = fmaf(c0, w.w, h[7]);        \
                w = WQ((DB) * 3 + 2);                                           \
                h[8] = fmaf(c0, w.x, h[8]);  h[9] = fmaf(c0, w.y, h[9]);        \
                h[10] = fmaf(c0, w.z, h[10]); h[11] = fmaf(c0, w.w, h[11]);     \
                w = WQ(((DB) + 1) * 3 + 0);                                     \
                h[0] = fmaf(c1, w.x, h[0]);  h[1] = fmaf(c1, w.y, h[1]);        \
                h[2] = fmaf(c1, w.z, h[2]);  h[3] = fmaf(c1, w.w, h[3]);        \
                w = WQ(((DB) + 1) * 3 + 1);                                     \
                h[4] = fmaf(c1, w.x, h[4]);  h[5] = fmaf(c1, w.y, h[5]);        \
                h[6] = fmaf(c1, w.z, h[6]);  h[7] = fmaf(c1, w.w, h[7]);        \
                w = WQ(((DB) + 1) * 3 + 2);                                     \
                h[8] = fmaf(c1, w.x, h[8]);  h[9] = fmaf(c1, w.y, h[9]);        \
                h[10] = fmaf(c1, w.z, h[10]); h[11] = fmaf(c1, w.w, h[11]);     \
            }
            DIMPAIR(ua.x, ub.x, c * 8 + 0)
            DIMPAIR(ua.y, ub.y, c * 8 + 2)
            DIMPAIR(ua.z, ub.z, c * 8 + 4)
            DIMPAIR(ua.w, ub.w, c * 8 + 6)
#undef DIMPAIR
#undef WQ
        }

        float lg = proj_b[0];
        #pragma unroll
        for (int k = 0; k < NH; ++k)
            lg = fmaf(fmaxf(h[k], 0.0f), proj_W[k], lg);
        lg *= TEMP_INV;
        if (!valid) lg = -INFINITY;
        lmax = fmaxf(lmax, lg);
        if (valid) expv_s[wv][p] = lg;       // park logit
    }

    // ---- wave-local softmax (shuffles only) ----
    #pragma unroll
    for (int o = 32; o > 0; o >>= 1) lmax = fmaxf(lmax, __shfl_xor(lmax, o));

    float lsum = 0.0f;
    #pragma unroll 1
    for (int r = 0; r < 6; ++r) {
        int p = r * 64 + lane;
        if (p < NPAIR) {
            float ev = __expf(expv_s[wv][p] - lmax);
            expv_s[wv][p] = ev;
            lsum += ev;
        }
    }
    if (lane < NPADQ - NPAIR) expv_s[wv][NPAIR + lane] = 0.0f;
    #pragma unroll
    for (int o = 32; o > 0; o >>= 1) lsum += __shfl_xor(lsum, o);

    __syncthreads();   // expv_s visible across lanes (same wave really)

    // ---- weighted sum: lane = dim; e in registers; static unrolled pairs ----
    float e_reg[N_SPARSE];
    #pragma unroll
    for (int f = 0; f < N_SPARSE; ++f) {
        const unsigned short* pp = &eb_s[wv][0][0] + f * EBSTR
            + ((((lane >> 3) + 2 * f) & 7) << 3) + (lane & 7);
        e_reg[f] = __uint_as_float(((unsigned)*pp) << 16);
    }

    const float4* evq = reinterpret_cast<const float4*>(&expv_s[wv][0]);
    float  acc = 0.0f;
    float4 sq4 = {0.f, 0.f, 0.f, 0.f};
    #pragma unroll
    for (int i = 0; i < N_SPARSE - 1; ++i) {
        #pragma unroll
        for (int j = i + 1; j < N_SPARSE; ++j) {
            const int p = (i * (51 - i)) / 2 + (j - i - 1);   // sequential
            if ((p & 3) == 0) sq4 = evq[p >> 2];
            const float s = ((p & 3) == 0) ? sq4.x :
                            ((p & 3) == 1) ? sq4.y :
                            ((p & 3) == 2) ? sq4.z : sq4.w;
            acc = fmaf(s, e_reg[i] * e_reg[j], acc);
        }
    }

    // ---- epilogue: dual wave reduce, sigmoid ----
    float red  = acc * pred_W[lane];
    float redp = p1t;
    #pragma unroll
    for (int o = 32; o > 0; o >>= 1) {
        red  += __shfl_xor(red,  o);
        redp += __shfl_xor(redp, o);
    }
    if (lane == 0) {
        float z = redp + lin_b[0] + red / lsum + pred_b[0];
        out[row] = 1.0f / (1.0f + __expf(-z));
    }
}

extern "C" void kernel_launch(void* const* d_in, const int* in_sizes, int n_in,
                              void* d_out, int out_size, void* d_ws, size_t ws_size,
                              hipStream_t stream)
{
    const float* dense_x = (const float*)d_in[0];
    const int*   sparse  = (const int*)  d_in[1];
    const float* emb     = (const float*)d_in[2];
    const float* attn_W  = (const float*)d_in[3];
    const float* attn_b  = (const float*)d_in[4];
    const float* proj_W  = (const float*)d_in[5];
    const float* proj_b  = (const float*)d_in[6];
    const float* lin_W   = (const float*)d_in[7];
    const float* lin_b   = (const float*)d_in[8];
    const float* pred_W  = (const float*)d_in[9];
    const float* pred_b  = (const float*)d_in[10];
    float* out = (float*)d_out;

    int rows = in_sizes[0] / N_DENSE;   // 8192
    afm_kernel<<<rows / 2, 128, 0, stream>>>(dense_x, sparse, emb, attn_W, attn_b,
                                             proj_W, proj_b, lin_W, lin_b,
                                             pred_W, pred_b, out);
}

// Round 6
// 53.417 us; speedup vs baseline: 3.7790x; 1.9722x over previous
//
#include <hip/hip_runtime.h>
#include <math.h>

#define N_DENSE  13
#define N_SPARSE 26
#define VOCAB    100000
#define EMB      64
#define NH       12
#define NPAIR    325
#define NTILE    21      // ceil(325/16) pair tiles
#define EBSTR    72      // u16 per eb_s row: 144B (16B-aligned rows)
#define ETSTR    40      // u16 per e_t row: 80B (16B-aligned rows)
#define NPADH    336     // logit/score slots (21*16)
#define TEMP_INV 10.0f

typedef __attribute__((ext_vector_type(8))) _Float16 f16x8;
typedef __attribute__((ext_vector_type(4))) float    f32x4;

// DPP row_shr reduction within each 16-lane row; result lands in lane (row base + 15).
#define DPP_STEP(x, ctrl)                                                        \
    x += __int_as_float(__builtin_amdgcn_update_dpp(                            \
            0, __float_as_int(x), ctrl, 0xF, 0xF, true))
#define DPP_ROWRED(x) do { DPP_STEP(x, 0x111); DPP_STEP(x, 0x112);              \
                           DPP_STEP(x, 0x114); DPP_STEP(x, 0x118); } while (0)

__global__ __launch_bounds__(128, 4) void afm_kernel(
    const float* __restrict__ dense_x,
    const int*   __restrict__ sparse_idx,
    const float* __restrict__ emb,
    const float* __restrict__ attn_W,
    const float* __restrict__ attn_b,
    const float* __restrict__ proj_W,
    const float* __restrict__ proj_b,
    const float* __restrict__ lin_W,
    const float* __restrict__ lin_b,
    const float* __restrict__ pred_W,
    const float* __restrict__ pred_b,
    float* __restrict__ out)
{
    const int tid  = threadIdx.x;
    const int lane = tid & 63;
    const int wv   = tid >> 6;        // wave = row slot (2 rows/block)
    const int q    = lane >> 4;       // MFMA k-group / C-row group
    const int c16  = lane & 15;       // MFMA A-row / C-col index
    const int row  = __builtin_amdgcn_readfirstlane(blockIdx.x * 2 + wv);

    __shared__ __align__(16) unsigned short eb_s[2][N_SPARSE][EBSTR]; // e row-major f16
    __shared__ __align__(16) unsigned short et_s[2][EMB][ETSTR];      // e transposed f16
    __shared__ __align__(16) unsigned short expv_s[2][NPADH];         // logits->scores f16

    // ---- zero e_t pad cols 26..31 (MFMA K reaches field 31) ----
    #pragma unroll
    for (int z = 0; z < 3; ++z)
        *reinterpret_cast<unsigned*>(&et_s[wv][lane][26 + 2 * z]) = 0u;

    // ---- gather: load f32 embeddings, store f16 row-major + transposed ----
    const int* sidx = sparse_idx + row * N_SPARSE;   // uniform base
    #pragma unroll 1
    for (int q2 = lane; q2 < N_SPARSE * 16; q2 += 64) {
        int f = q2 >> 4, d4 = q2 & 15;
        int id = sidx[f];
        float4 v = *reinterpret_cast<const float4*>(
            emb + ((size_t)f * VOCAB + (size_t)id) * EMB + d4 * 4);
        auto h01 = __builtin_amdgcn_cvt_pkrtz(v.x, v.y);
        auto h23 = __builtin_amdgcn_cvt_pkrtz(v.z, v.w);
        uint2 pk;
        __builtin_memcpy(&pk.x, &h01, 4);
        __builtin_memcpy(&pk.y, &h23, 4);
        *reinterpret_cast<uint2*>(&eb_s[wv][f][d4 * 4]) = pk;   // 8B aligned
        et_s[wv][d4 * 4 + 0][f] = (unsigned short)(pk.x & 0xffffu);
        et_s[wv][d4 * 4 + 1][f] = (unsigned short)(pk.x >> 16);
        et_s[wv][d4 * 4 + 2][f] = (unsigned short)(pk.y & 0xffffu);
        et_s[wv][d4 * 4 + 3][f] = (unsigned short)(pk.y >> 16);
    }

    // ---- part_1 term per lane (exact f32) ----
    float p1t = 0.0f;
    if (lane < N_DENSE) {
        p1t = dense_x[row * N_DENSE + lane] * lin_W[lane];
    } else if (lane < N_DENSE + N_SPARSE) {
        p1t = (float)sidx[lane - N_DENSE] * lin_W[lane];
    }

    // ---- W B-frags (loop-invariant, 8 VGPRs): lane holds W[k][col=c16] ----
    f16x8 wf[2];
    {
        const bool hok = (c16 < NH);
        const int  hc  = hok ? c16 : 0;
        #pragma unroll
        for (int kt = 0; kt < 2; ++kt) {
            union { f16x8 v; unsigned u32[4]; } u;
            #pragma unroll
            for (int jp = 0; jp < 4; ++jp) {
                int d0 = kt * 32 + q * 8 + jp * 2;
                float w0 = attn_W[d0 * NH + hc];
                float w1 = attn_W[(d0 + 1) * NH + hc];
                if (!hok) { w0 = 0.f; w1 = 0.f; }
                auto hh = __builtin_amdgcn_cvt_pkrtz(w0, w1);
                __builtin_memcpy(&u.u32[jp], &hh, 4);
            }
            wf[kt] = u.v;
        }
    }
    const float b_reg  = (c16 < NH) ? attn_b[c16] : 0.0f;
    const float pw_reg = (c16 < NH) ? proj_W[c16] : 0.0f;
    const float pb     = proj_b[0];

    // ---- logit tiles: 16 pairs per MFMA pair-tile, K=64 in 2 MFMAs ----
    float lmax_h = -INFINITY;   // valid on lanes c16==15
    #pragma unroll 1
    for (int t = 0; t < NTILE; ++t) {
        int pc = t * 16 + c16;
        pc = pc > NPAIR - 1 ? NPAIR - 1 : pc;
        float sf = sqrtf((float)(2601 - 8 * pc));
        int i = (int)((51.0f - sf) * 0.5f);
        int st = (i * (51 - i)) >> 1;
        if (pc < st) { --i; st = (i * (51 - i)) >> 1; }
        else { int st2 = ((i + 1) * (50 - i)) >> 1; if (pc >= st2) { ++i; st = st2; } }
        int j = i + 1 + (pc - st);

        const f16x8* pi = reinterpret_cast<const f16x8*>(&eb_s[wv][i][q * 8]);
        const f16x8* pj = reinterpret_cast<const f16x8*>(&eb_s[wv][j][q * 8]);
        f16x8 ca = pi[0] * pj[0];     // cross dims q*8..+7        (A-frag kt0)
        f16x8 cb = pi[4] * pj[4];     // cross dims 32+q*8..+7     (A-frag kt1)

        f32x4 acc = {0.f, 0.f, 0.f, 0.f};
        acc = __builtin_amdgcn_mfma_f32_16x16x32_f16(ca, wf[0], acc, 0, 0, 0);
        acc = __builtin_amdgcn_mfma_f32_16x16x32_f16(cb, wf[1], acc, 0, 0, 0);

        // relu(H+b)*proj_W, reduce over hidden (c16) via DPP; logit lands c16==15
        float r0 = fmaxf(acc[0] + b_reg, 0.f) * pw_reg;
        float r1 = fmaxf(acc[1] + b_reg, 0.f) * pw_reg;
        float r2 = fmaxf(acc[2] + b_reg, 0.f) * pw_reg;
        float r3 = fmaxf(acc[3] + b_reg, 0.f) * pw_reg;
        DPP_ROWRED(r0); DPP_ROWRED(r1); DPP_ROWRED(r2); DPP_ROWRED(r3);

        if (c16 == 15) {
            float l0 = (r0 + pb) * TEMP_INV;
            float l1 = (r1 + pb) * TEMP_INV;
            float l2 = (r2 + pb) * TEMP_INV;
            float l3 = (r3 + pb) * TEMP_INV;
            lmax_h = fmaxf(lmax_h, fmaxf(fmaxf(l0, l1), fmaxf(l2, l3)));
            auto s01 = __builtin_amdgcn_cvt_pkrtz(l0, l1);
            auto s23 = __builtin_amdgcn_cvt_pkrtz(l2, l3);
            uint2 pk;
            __builtin_memcpy(&pk.x, &s01, 4);
            __builtin_memcpy(&pk.y, &s23, 4);
            *reinterpret_cast<uint2*>(&expv_s[wv][t * 16 + q * 4]) = pk;
        }
    }

    // ---- wave softmax: max, exp, sum (scores stay unnormalized f16) ----
    float gm = (c16 == 15) ? lmax_h : -INFINITY;
    #pragma unroll
    for (int o = 32; o > 0; o >>= 1) gm = fmaxf(gm, __shfl_xor(gm, o));

    float lsum = 0.0f;
    #pragma unroll 1
    for (int rr = 0; rr < 6; ++rr) {
        int p = rr * 64 + lane;
        if (p < NPAIR) {
            unsigned short lb = expv_s[wv][p];
            _Float16 lf;
            __builtin_memcpy(&lf, &lb, 2);
            float ev = __expf((float)lf - gm);
            _Float16 eh = (_Float16)ev;
            unsigned short ebts;
            __builtin_memcpy(&ebts, &eh, 2);
            expv_s[wv][p] = ebts;
            lsum += ev;
        }
    }
    #pragma unroll
    for (int o = 32; o > 0; o >>= 1) lsum += __shfl_xor(lsum, o);

    // ---- S A-frags: S[i][b] = score(pair(i,b)), 0 on diag/pad ----
    f16x8 sfr[2];
    #pragma unroll
    for (int it = 0; it < 2; ++it) {
        union { f16x8 v; unsigned short u[8]; } su;
        int i_ = it * 16 + c16;
        #pragma unroll
        for (int jj = 0; jj < 8; ++jj) {
            int b  = q * 8 + jj;
            int mn = min(i_, b), mx = max(i_, b);
            int pidx = ((mn * (51 - mn)) >> 1) + (mx - mn - 1);
            bool ok = (i_ < N_SPARSE) && (b < N_SPARSE) && (b != i_);
            int pcl = ok ? pidx : 0;
            unsigned short sv = expv_s[wv][pcl];
            su.u[jj] = ok ? sv : (unsigned short)0;
        }
        sfr[it] = su.v;
    }

    // ---- G = S @ E (8 MFMAs) fused with att.pred_W epilogue ----
    float vsum = 0.0f;
    #pragma unroll
    for (int nt = 0; nt < 4; ++nt) {
        const f16x8 ef = *reinterpret_cast<const f16x8*>(
            &et_s[wv][nt * 16 + c16][q * 8]);                 // B: E[k=field][n=dim]
        f32x4 g0 = {0.f, 0.f, 0.f, 0.f};
        f32x4 g1 = {0.f, 0.f, 0.f, 0.f};
        g0 = __builtin_amdgcn_mfma_f32_16x16x32_f16(sfr[0], ef, g0, 0, 0, 0);
        g1 = __builtin_amdgcn_mfma_f32_16x16x32_f16(sfr[1], ef, g1, 0, 0, 0);

        float pw4 = pred_W[nt * 16 + c16];
        float part = 0.0f;
        #pragma unroll
        for (int r = 0; r < 4; ++r) {
            int i0 = q * 4 + r;
            unsigned short e0 = et_s[wv][nt * 16 + c16][i0];
            unsigned short e1 = et_s[wv][nt * 16 + c16][i0 + 16];
            _Float16 h0, h1;
            __builtin_memcpy(&h0, &e0, 2);
            __builtin_memcpy(&h1, &e1, 2);
            part = fmaf((float)h0, g0[r], part);
            part = fmaf((float)h1, g1[r], part);
        }
        vsum = fmaf(part, pw4, vsum);
    }

    // ---- final: reduce vsum (att.pred_W, double-counted 2x) and part_1 ----
    float p1 = p1t;
    #pragma unroll
    for (int o = 32; o > 0; o >>= 1) {
        vsum += __shfl_xor(vsum, o);
        p1   += __shfl_xor(p1, o);
    }
    if (lane == 0) {
        float z = p1 + lin_b[0] + 0.5f * vsum / lsum + pred_b[0];
        out[row] = 1.0f / (1.0f + __expf(-z));
    }
}

extern "C" void kernel_launch(void* const* d_in, const int* in_sizes, int n_in,
                              void* d_out, int out_size, void* d_ws, size_t ws_size,
                              hipStream_t stream)
{
    const float* dense_x = (const float*)d_in[0];
    const int*   sparse  = (const int*)  d_in[1];
    const float* emb     = (const float*)d_in[2];
    const float* attn_W  = (const float*)d_in[3];
    const float* attn_b  = (const float*)d_in[4];
    const float* proj_W  = (const float*)d_in[5];
    const float* proj_b  = (const float*)d_in[6];
    const float* lin_W   = (const float*)d_in[7];
    const float* lin_b   = (const float*)d_in[8];
    const float* pred_W  = (const float*)d_in[9];
    const float* pred_b  = (const float*)d_in[10];
    float* out = (float*)d_out;

    int rows = in_sizes[0] / N_DENSE;   // 8192
    afm_kernel<<<rows / 2, 128, 0, stream>>>(dense_x, sparse, emb, attn_W, attn_b,
                                             proj_W, proj_b, lin_W, lin_b,
                                             pred_W, pred_b, out);
}